// Round 11
// baseline (436.662 us; speedup 1.0000x reference)
//
#include <hip/hip_runtime.h>
#include <cstdint>
#include <cstddef>

typedef unsigned short u16;
typedef __attribute__((ext_vector_type(4))) float f32x4;
typedef __attribute__((ext_vector_type(8))) __bf16 bf16x8;
typedef __attribute__((ext_vector_type(8))) unsigned short u16x8;

#define M_TOTAL 100352   // B*T*N = 8*64*196
#define K_DIM   384
#define QKV_N   1152
#define NHEADS  6
#define NPAT    196
#define SCL     0.125f   // HEAD_DIM^-0.5

__device__ __forceinline__ u16 f2bf(float f) {
    unsigned int u = __builtin_bit_cast(unsigned int, f);
    u += 0x7fffu + ((u >> 16) & 1u);   // RNE
    return (u16)(u >> 16);
}

__device__ __forceinline__ unsigned int pack2(float a, float b) {
    union { __bf16 h[2]; unsigned int u; } p;
    p.h[0] = (__bf16)a; p.h[1] = (__bf16)b;
    return p.u;
}

__device__ __forceinline__ void gload16(const void* g, void* l) {
    __builtin_amdgcn_global_load_lds(
        (const __attribute__((address_space(1))) unsigned int*)g,
        (__attribute__((address_space(3))) unsigned int*)l, 16, 0, 0);
}

// chunked XCD swizzle; requires gridDim.x % 8 == 0 (true for all launches here)
__device__ __forceinline__ int xcd_swz(int bid, int per_xcd) {
    return (bid & 7) * per_xcd + (bid >> 3);
}

// ---------------- fp32 -> bf16 convert (8 elems/thread) ----------------
__global__ void cvt_bf16_kern(const float* __restrict__ in, u16* __restrict__ out, int n8) {
    int i = blockIdx.x * 256 + threadIdx.x;
    if (i >= n8) return;
    const float4* p = (const float4*)in + (size_t)i * 2;
    float4 a = p[0], b = p[1];
    u16x8 o;
    o[0]=f2bf(a.x); o[1]=f2bf(a.y); o[2]=f2bf(a.z); o[3]=f2bf(a.w);
    o[4]=f2bf(b.x); o[5]=f2bf(b.y); o[6]=f2bf(b.z); o[7]=f2bf(b.w);
    *((u16x8*)out + i) = o;
}

// W_proj convert with column permute: out[o][h*64+d] = W[o][d*6+h]
__global__ void cvt_wproj_kern(const float* __restrict__ in, u16* __restrict__ out) {
    int i = blockIdx.x * 256 + threadIdx.x;   // i = o*384 + c''
    int o = i / 384;
    int c = i - o * 384;        // NOTE: 384 is not pow2 — cannot use i & 383
    int d = c & 63, h = c >> 6; // c'' = h*64 + d (64 IS pow2)
    out[i] = f2bf(in[(size_t)o * 384 + d * 6 + h]);
}

// ---------------- GEMM: C[M,NOUT] = A[M,384] * Bw[NOUT,384]^T + bias ----------------
// R3-verified 2-phase structure (best measured: 573 TF, conflicts 0). T2
// XOR-swizzle both tiles (rule 21: linear gload_lds dest + inverse-swizzled
// global source + swizzled ds_read address).
// Round-11 single variable: __launch_bounds__ (256,2)->(256,4). LDS 32KB
// permits 5 blocks/CU and VGPR=60 permits 8 waves/SIMD, but measured occupancy
// was only ~38% (~3 blocks/CU). Declaring min 4 waves/EU requests 4 blocks/CU;
// cross-block stage/MFMA overlap (m114) is the only mechanism that has moved
// this loop. VGPR budget at 4 waves/EU = 128 >= 60: no spill risk.
template<int NOUT, bool BF16OUT, bool QSCALE>
__global__ __launch_bounds__(256, 4) void gemm_kern(
        const u16* __restrict__ A, const u16* __restrict__ Bw,
        const float* __restrict__ bias, void* __restrict__ outp) {
    constexpr int NB = NOUT / 128;
    constexpr int PER_XCD = (M_TOTAL / 128) * NB / 8;
    __shared__ u16 As[128 * 64];
    __shared__ u16 Bs[128 * 64];
    int wg = xcd_swz(blockIdx.x, PER_XCD);
    int bm = wg / NB, bn = wg % NB;
    int tid = threadIdx.x;
    int l = tid & 63, w = tid >> 6;
    int wr = w >> 1, wc = w & 1;
    f32x4 acc[4][4] = {};
    const u16* Ag = A + (size_t)bm * 128 * K_DIM;
    const u16* Bg = Bw + (size_t)bn * 128 * K_DIM;

    for (int ks = 0; ks < 6; ++ks) {
#pragma unroll
        for (int i = 0; i < 4; ++i) {
            int c = i * 256 + tid;
            int row = c >> 3, cc = c & 7;
            int scc = cc ^ (row & 7);   // inverse-swizzled source chunk
            gload16(Ag + (size_t)row * K_DIM + ks * 64 + scc * 8, (u16*)As + c * 8);
            gload16(Bg + (size_t)row * K_DIM + ks * 64 + scc * 8, (u16*)Bs + c * 8);
        }
        __syncthreads();
#pragma unroll
        for (int kk = 0; kk < 2; ++kk) {
            bf16x8 af[4], bfr[4];
            int ccr = kk * 4 + (l >> 4);
#pragma unroll
            for (int m = 0; m < 4; ++m) {
                int ar = wr * 64 + m * 16 + (l & 15);
                af[m] = *(const bf16x8*)&As[ar * 64 + ((ccr ^ (ar & 7)) << 3)];
            }
#pragma unroll
            for (int n = 0; n < 4; ++n) {
                int br = wc * 64 + n * 16 + (l & 15);
                bfr[n] = *(const bf16x8*)&Bs[br * 64 + ((ccr ^ (br & 7)) << 3)];
            }
#pragma unroll
            for (int m = 0; m < 4; ++m)
#pragma unroll
                for (int n = 0; n < 4; ++n)
                    acc[m][n] = __builtin_amdgcn_mfma_f32_16x16x32_bf16(af[m], bfr[n], acc[m][n], 0, 0, 0);
        }
        __syncthreads();
    }
    // epilogue
#pragma unroll
    for (int n = 0; n < 4; ++n) {
        int col = bn * 128 + wc * 64 + n * 16 + (l & 15);
        float bv = bias[col];
#pragma unroll
        for (int m = 0; m < 4; ++m) {
            int row0 = bm * 128 + wr * 64 + m * 16 + (l >> 4) * 4;
#pragma unroll
            for (int r = 0; r < 4; ++r) {
                float v = acc[m][n][r] + bv;
                if constexpr (QSCALE) { if (col < 384) v *= SCL; }
                if constexpr (BF16OUT)
                    ((u16*)outp)[(size_t)(row0 + r) * NOUT + col] = f2bf(v);
                else
                    ((float*)outp)[(size_t)(row0 + r) * NOUT + col] = v;
            }
        }
    }
}

// ---------------- attention per (b,t,h): 196x196 over head_dim 64 ----------------
// Round-8 verified (best measured): swapped QK^T + permuted K-row staging
// (P never leaves the lane), 512 threads / 8 waves, launch_bounds(512,4)
// -> 16 waves/CU.
//   key n at LDS row rho(n) = (2*(n>>5)+((n>>2)&1))*16 + ((n>>3)&3)*4 + (n&3)
//   lane (lg,lr) frag f holds S[q=lr][key = 32*(f>>1) + lg*8 + 4*(f&1) + r].
__device__ __forceinline__ void attn_qt(
        const u16* __restrict__ k_lds, const u16* __restrict__ vT,
        u16* __restrict__ osc, size_t m_base, int h, int lr, int lg,
        int qt, bf16x8 bq0, bf16x8 bq1) {
    // S^T = K Q^T : 13 computed frags (virtual frag 13 is identically zero)
    f32x4 s[13];
    __builtin_amdgcn_s_setprio(1);
#pragma unroll
    for (int f = 0; f < 13; ++f) {
        f32x4 a = {};
        bf16x8 k0 = *(const bf16x8*)&k_lds[(f * 16 + lr) * 72 + lg * 8];
        a = __builtin_amdgcn_mfma_f32_16x16x32_bf16(k0, bq0, a, 0, 0, 0);
        bf16x8 k1 = *(const bf16x8*)&k_lds[(f * 16 + lr) * 72 + 32 + lg * 8];
        a = __builtin_amdgcn_mfma_f32_16x16x32_bf16(k1, bq1, a, 0, 0, 0);
        s[f] = a;
    }
    __builtin_amdgcn_s_setprio(0);
    // softmax over the lane's row (logits tiny: no max subtraction); 4 ILP chains
    float p0 = 0.f, p1 = 0.f, p2 = 0.f, p3 = 0.f;
#pragma unroll
    for (int f = 0; f < 13; ++f) {
        float e0 = __expf(s[f][0]), e1 = __expf(s[f][1]);
        float e2 = __expf(s[f][2]), e3 = __expf(s[f][3]);
        if (f == 12 && lg > 0) { e0 = 0.f; e1 = 0.f; e2 = 0.f; e3 = 0.f; }
        s[f][0] = e0; s[f][1] = e1; s[f][2] = e2; s[f][3] = e3;
        p0 += e0; p1 += e1; p2 += e2; p3 += e3;
    }
    float sum = (p0 + p1) + (p2 + p3);
    sum += __shfl_xor(sum, 16);
    sum += __shfl_xor(sum, 32);
    float rs = __builtin_amdgcn_rcpf(sum);

    // pack P*rs to bf16 pairs, lane-local; frag 13 is zero
    unsigned int pk0[14], pk1[14];
#pragma unroll
    for (int f = 0; f < 13; ++f) {
        pk0[f] = pack2(s[f][0] * rs, s[f][1] * rs);
        pk1[f] = pack2(s[f][2] * rs, s[f][3] * rs);
    }
    pk0[13] = 0u; pk1[13] = 0u;

    // O = P V : A-frag assembled from the lane's own packs (static idx)
    f32x4 o[4] = {};
    __builtin_amdgcn_s_setprio(1);
#pragma unroll
    for (int kb = 0; kb < 7; ++kb) {
        union { unsigned int u[4]; bf16x8 v; } pa;
        pa.u[0] = pk0[2 * kb];     pa.u[1] = pk1[2 * kb];
        pa.u[2] = pk0[2 * kb + 1]; pa.u[3] = pk1[2 * kb + 1];
#pragma unroll
        for (int j = 0; j < 4; ++j) {
            bf16x8 bv = *(const bf16x8*)&vT[(j * 16 + lr) * 232 + kb * 32 + lg * 8];
            o[j] = __builtin_amdgcn_mfma_f32_16x16x32_bf16(pa.v, bv, o[j], 0, 0, 0);
        }
    }
    __builtin_amdgcn_s_setprio(0);
    // store O (h-major col layout; denom already folded into P)
    int q0 = qt * 16;
#pragma unroll
    for (int j = 0; j < 4; ++j) {
#pragma unroll
        for (int r = 0; r < 4; ++r) {
            int q = q0 + lg * 4 + r;
            if (q < 196)
                osc[(m_base + q) * 384 + h * 64 + j * 16 + lr] = f2bf(o[j][r]);
        }
    }
}

__global__ __launch_bounds__(512, 4) void attn_kern(const u16* __restrict__ qkv,
                                                    u16* __restrict__ osc) {
    __shared__ u16 k_lds[224 * 72];   // [perm-row][d], stride 72 (16B-aligned rows)
    __shared__ u16 vT[64 * 232];      // [d][key], natural key order, zero-padded

    int wg = xcd_swz(blockIdx.x, 384);
    int h = wg % NHEADS;
    int bt = wg / NHEADS;
    size_t m_base = (size_t)bt * NPAT;
    int tid = threadIdx.x, l = tid & 63, w = tid >> 6;   // w in 0..7
    int lr = l & 15, lg = l >> 4;

    // prefetch this wave's first Q tile (issue-early: overlaps staging latency)
    bf16x8 q00, q01;
    {
        int qrow = w * 16 + lr; if (qrow > 195) qrow = 195;
        const u16* qs = qkv + (m_base + qrow) * QKV_N + h * 64 + lg * 8;
        q00 = *(const bf16x8*)qs;
        q01 = *(const bf16x8*)(qs + 32);
    }

    // stage K rows 0..223 (zeros for key >= 196) at permuted rows. 8 lanes/row.
    {
        int d0 = (tid & 7) * 8;
#pragma unroll
        for (int it = 0; it < 4; ++it) {
            int n = it * 64 + (tid >> 3);
            if (n < 224) {
                u16x8 val = {};
                if (n < 196)
                    val = *(const u16x8*)(qkv + (m_base + n) * QKV_N + 384 + h * 64 + d0);
                int pr = (2 * (n >> 5) + ((n >> 2) & 1)) * 16 + ((n >> 3) & 3) * 4 + (n & 3);
                *(u16x8*)&k_lds[pr * 72 + d0] = val;
            }
        }
    }
    // stage V transposed: wave w owns d rows w*8..w*8+7; lane = key row.
    {
        int d0 = w * 8;
#pragma unroll
        for (int it = 0; it < 4; ++it) {
            int n = it * 64 + l;
            if (n < 232) {
                u16x8 v0 = {};
                if (n < 196)
                    v0 = *(const u16x8*)(qkv + (m_base + n) * QKV_N + 768 + h * 64 + d0);
#pragma unroll
                for (int j = 0; j < 8; ++j)
                    vT[(d0 + j) * 232 + n] = v0[j];
            }
        }
    }
    __syncthreads();

    // qt = w, then w+8 (waves 5..7 have only one tile)
    attn_qt(k_lds, vT, osc, m_base, h, lr, lg, w, q00, q01);
    int qt1 = w + 8;
    if (qt1 < 13) {
        int qrow = qt1 * 16 + lr; if (qrow > 195) qrow = 195;
        const u16* qs = qkv + (m_base + qrow) * QKV_N + h * 64 + lg * 8;
        attn_qt(k_lds, vT, osc, m_base, h, lr, lg, qt1,
                *(const bf16x8*)qs, *(const bf16x8*)(qs + 32));
    }
}

extern "C" void kernel_launch(void* const* d_in, const int* in_sizes, int n_in,
                              void* d_out, int out_size, void* d_ws, size_t ws_size,
                              hipStream_t stream) {
    const float* x     = (const float*)d_in[0];
    const float* Wqkv  = (const float*)d_in[1];
    const float* bqkv  = (const float*)d_in[2];
    const float* Wproj = (const float*)d_in[3];
    const float* bproj = (const float*)d_in[4];

    // workspace layout (all bf16/u16):
    //   xbf    : M*384      (x in bf16; reused as attention output)
    //   qkvb   : M*1152
    //   wqkvb  : 1152*384
    //   wprojb : 384*384 (col-permuted)
    const size_t need = ((size_t)M_TOTAL * 384 + (size_t)M_TOTAL * QKV_N
                         + (size_t)QKV_N * K_DIM + (size_t)K_DIM * K_DIM) * 2;
    if (ws_size < need) {
        hipMemsetAsync(d_out, 0, (size_t)out_size * 4, stream);
        return;
    }

    u16* xbf    = (u16*)d_ws;
    u16* qkvb   = xbf + (size_t)M_TOTAL * 384;
    u16* wqkvb  = qkvb + (size_t)M_TOTAL * QKV_N;
    u16* wprojb = wqkvb + (size_t)QKV_N * K_DIM;

    cvt_bf16_kern<<<18816, 256, 0, stream>>>(x, xbf, 4816896);
    cvt_bf16_kern<<<216, 256, 0, stream>>>(Wqkv, wqkvb, 55296);
    cvt_wproj_kern<<<576, 256, 0, stream>>>(Wproj, wprojb);

    gemm_kern<QKV_N, true, true><<<7056, 256, 0, stream>>>(xbf, wqkvb, bqkv, qkvb);
    attn_kern<<<3072, 512, 0, stream>>>(qkvb, xbf);
    gemm_kern<384, false, false><<<2352, 256, 0, stream>>>(xbf, wprojb, bproj, (float*)d_out);
}

// Round 12
// 329.027 us; speedup vs baseline: 1.3271x; 1.3271x over previous
//
#include <hip/hip_runtime.h>
#include <cstdint>
#include <cstddef>

typedef unsigned short u16;
typedef __attribute__((ext_vector_type(4))) float f32x4;
typedef __attribute__((ext_vector_type(8))) __bf16 bf16x8;
typedef __attribute__((ext_vector_type(8))) unsigned short u16x8;

#define M_TOTAL 100352   // B*T*N = 8*64*196
#define K_DIM   384
#define QKV_N   1152
#define NHEADS  6
#define NPAT    196
#define SCL     0.125f   // HEAD_DIM^-0.5

__device__ __forceinline__ u16 f2bf(float f) {
    unsigned int u = __builtin_bit_cast(unsigned int, f);
    u += 0x7fffu + ((u >> 16) & 1u);   // RNE
    return (u16)(u >> 16);
}

__device__ __forceinline__ unsigned int pack2(float a, float b) {
    union { __bf16 h[2]; unsigned int u; } p;
    p.h[0] = (__bf16)a; p.h[1] = (__bf16)b;
    return p.u;
}

__device__ __forceinline__ void gload16(const void* g, void* l) {
    __builtin_amdgcn_global_load_lds(
        (const __attribute__((address_space(1))) unsigned int*)g,
        (__attribute__((address_space(3))) unsigned int*)l, 16, 0, 0);
}

// chunked XCD swizzle; requires gridDim.x % 8 == 0 (true for all launches here)
__device__ __forceinline__ int xcd_swz(int bid, int per_xcd) {
    return (bid & 7) * per_xcd + (bid >> 3);
}

// ---------------- fp32 -> bf16 convert (8 elems/thread) ----------------
__global__ void cvt_bf16_kern(const float* __restrict__ in, u16* __restrict__ out, int n8) {
    int i = blockIdx.x * 256 + threadIdx.x;
    if (i >= n8) return;
    const float4* p = (const float4*)in + (size_t)i * 2;
    float4 a = p[0], b = p[1];
    u16x8 o;
    o[0]=f2bf(a.x); o[1]=f2bf(a.y); o[2]=f2bf(a.z); o[3]=f2bf(a.w);
    o[4]=f2bf(b.x); o[5]=f2bf(b.y); o[6]=f2bf(b.z); o[7]=f2bf(b.w);
    *((u16x8*)out + i) = o;
}

// W_proj convert with column permute: out[o][h*64+d] = W[o][d*6+h]
__global__ void cvt_wproj_kern(const float* __restrict__ in, u16* __restrict__ out) {
    int i = blockIdx.x * 256 + threadIdx.x;   // i = o*384 + c''
    int o = i / 384;
    int c = i - o * 384;        // NOTE: 384 is not pow2 — cannot use i & 383
    int d = c & 63, h = c >> 6; // c'' = h*64 + d (64 IS pow2)
    out[i] = f2bf(in[(size_t)o * 384 + d * 6 + h]);
}

// ---------------- GEMM: C[M,NOUT] = A[M,384] * Bw[NOUT,384]^T + bias ----------------
// R3/R8-verified 2-phase structure — best measured (573 TF, conflicts 0,
// qkv 155 us). T2 XOR-swizzle both tiles (rule 21: linear gload_lds dest +
// inverse-swizzled global source + swizzled ds_read address).
// __launch_bounds__(256,2) is LOAD-BEARING (round-11 A/B): requesting 4
// blocks/CU blew the per-CU L2 working set -> A-panel rereads spilled to HBM
// (FETCH 47->128 MB) and C-writes lost write-combining (WRITE 280->488 MB),
// qkv 155->226 us. Keep (256,2).
template<int NOUT, bool BF16OUT, bool QSCALE>
__global__ __launch_bounds__(256, 2) void gemm_kern(
        const u16* __restrict__ A, const u16* __restrict__ Bw,
        const float* __restrict__ bias, void* __restrict__ outp) {
    constexpr int NB = NOUT / 128;
    constexpr int PER_XCD = (M_TOTAL / 128) * NB / 8;
    __shared__ u16 As[128 * 64];
    __shared__ u16 Bs[128 * 64];
    int wg = xcd_swz(blockIdx.x, PER_XCD);
    int bm = wg / NB, bn = wg % NB;
    int tid = threadIdx.x;
    int l = tid & 63, w = tid >> 6;
    int wr = w >> 1, wc = w & 1;
    f32x4 acc[4][4] = {};
    const u16* Ag = A + (size_t)bm * 128 * K_DIM;
    const u16* Bg = Bw + (size_t)bn * 128 * K_DIM;

    for (int ks = 0; ks < 6; ++ks) {
#pragma unroll
        for (int i = 0; i < 4; ++i) {
            int c = i * 256 + tid;
            int row = c >> 3, cc = c & 7;
            int scc = cc ^ (row & 7);   // inverse-swizzled source chunk
            gload16(Ag + (size_t)row * K_DIM + ks * 64 + scc * 8, (u16*)As + c * 8);
            gload16(Bg + (size_t)row * K_DIM + ks * 64 + scc * 8, (u16*)Bs + c * 8);
        }
        __syncthreads();
#pragma unroll
        for (int kk = 0; kk < 2; ++kk) {
            bf16x8 af[4], bfr[4];
            int ccr = kk * 4 + (l >> 4);
#pragma unroll
            for (int m = 0; m < 4; ++m) {
                int ar = wr * 64 + m * 16 + (l & 15);
                af[m] = *(const bf16x8*)&As[ar * 64 + ((ccr ^ (ar & 7)) << 3)];
            }
#pragma unroll
            for (int n = 0; n < 4; ++n) {
                int br = wc * 64 + n * 16 + (l & 15);
                bfr[n] = *(const bf16x8*)&Bs[br * 64 + ((ccr ^ (br & 7)) << 3)];
            }
#pragma unroll
            for (int m = 0; m < 4; ++m)
#pragma unroll
                for (int n = 0; n < 4; ++n)
                    acc[m][n] = __builtin_amdgcn_mfma_f32_16x16x32_bf16(af[m], bfr[n], acc[m][n], 0, 0, 0);
        }
        __syncthreads();
    }
    // epilogue
#pragma unroll
    for (int n = 0; n < 4; ++n) {
        int col = bn * 128 + wc * 64 + n * 16 + (l & 15);
        float bv = bias[col];
#pragma unroll
        for (int m = 0; m < 4; ++m) {
            int row0 = bm * 128 + wr * 64 + m * 16 + (l >> 4) * 4;
#pragma unroll
            for (int r = 0; r < 4; ++r) {
                float v = acc[m][n][r] + bv;
                if constexpr (QSCALE) { if (col < 384) v *= SCL; }
                if constexpr (BF16OUT)
                    ((u16*)outp)[(size_t)(row0 + r) * NOUT + col] = f2bf(v);
                else
                    ((float*)outp)[(size_t)(row0 + r) * NOUT + col] = v;
            }
        }
    }
}

// ---------------- attention per (b,t,h): 196x196 over head_dim 64 ----------------
// Round-8 verified (best measured): swapped QK^T + permuted K-row staging
// (P never leaves the lane), 512 threads / 8 waves, launch_bounds(512,4)
// -> 16 waves/CU.
//   key n at LDS row rho(n) = (2*(n>>5)+((n>>2)&1))*16 + ((n>>3)&3)*4 + (n&3)
//   lane (lg,lr) frag f holds S[q=lr][key = 32*(f>>1) + lg*8 + 4*(f&1) + r].
__device__ __forceinline__ void attn_qt(
        const u16* __restrict__ k_lds, const u16* __restrict__ vT,
        u16* __restrict__ osc, size_t m_base, int h, int lr, int lg,
        int qt, bf16x8 bq0, bf16x8 bq1) {
    // S^T = K Q^T : 13 computed frags (virtual frag 13 is identically zero)
    f32x4 s[13];
    __builtin_amdgcn_s_setprio(1);
#pragma unroll
    for (int f = 0; f < 13; ++f) {
        f32x4 a = {};
        bf16x8 k0 = *(const bf16x8*)&k_lds[(f * 16 + lr) * 72 + lg * 8];
        a = __builtin_amdgcn_mfma_f32_16x16x32_bf16(k0, bq0, a, 0, 0, 0);
        bf16x8 k1 = *(const bf16x8*)&k_lds[(f * 16 + lr) * 72 + 32 + lg * 8];
        a = __builtin_amdgcn_mfma_f32_16x16x32_bf16(k1, bq1, a, 0, 0, 0);
        s[f] = a;
    }
    __builtin_amdgcn_s_setprio(0);
    // softmax over the lane's row (logits tiny: no max subtraction); 4 ILP chains
    float p0 = 0.f, p1 = 0.f, p2 = 0.f, p3 = 0.f;
#pragma unroll
    for (int f = 0; f < 13; ++f) {
        float e0 = __expf(s[f][0]), e1 = __expf(s[f][1]);
        float e2 = __expf(s[f][2]), e3 = __expf(s[f][3]);
        if (f == 12 && lg > 0) { e0 = 0.f; e1 = 0.f; e2 = 0.f; e3 = 0.f; }
        s[f][0] = e0; s[f][1] = e1; s[f][2] = e2; s[f][3] = e3;
        p0 += e0; p1 += e1; p2 += e2; p3 += e3;
    }
    float sum = (p0 + p1) + (p2 + p3);
    sum += __shfl_xor(sum, 16);
    sum += __shfl_xor(sum, 32);
    float rs = __builtin_amdgcn_rcpf(sum);

    // pack P*rs to bf16 pairs, lane-local; frag 13 is zero
    unsigned int pk0[14], pk1[14];
#pragma unroll
    for (int f = 0; f < 13; ++f) {
        pk0[f] = pack2(s[f][0] * rs, s[f][1] * rs);
        pk1[f] = pack2(s[f][2] * rs, s[f][3] * rs);
    }
    pk0[13] = 0u; pk1[13] = 0u;

    // O = P V : A-frag assembled from the lane's own packs (static idx)
    f32x4 o[4] = {};
    __builtin_amdgcn_s_setprio(1);
#pragma unroll
    for (int kb = 0; kb < 7; ++kb) {
        union { unsigned int u[4]; bf16x8 v; } pa;
        pa.u[0] = pk0[2 * kb];     pa.u[1] = pk1[2 * kb];
        pa.u[2] = pk0[2 * kb + 1]; pa.u[3] = pk1[2 * kb + 1];
#pragma unroll
        for (int j = 0; j < 4; ++j) {
            bf16x8 bv = *(const bf16x8*)&vT[(j * 16 + lr) * 232 + kb * 32 + lg * 8];
            o[j] = __builtin_amdgcn_mfma_f32_16x16x32_bf16(pa.v, bv, o[j], 0, 0, 0);
        }
    }
    __builtin_amdgcn_s_setprio(0);
    // store O (h-major col layout; denom already folded into P)
    int q0 = qt * 16;
#pragma unroll
    for (int j = 0; j < 4; ++j) {
#pragma unroll
        for (int r = 0; r < 4; ++r) {
            int q = q0 + lg * 4 + r;
            if (q < 196)
                osc[(m_base + q) * 384 + h * 64 + j * 16 + lr] = f2bf(o[j][r]);
        }
    }
}

__global__ __launch_bounds__(512, 4) void attn_kern(const u16* __restrict__ qkv,
                                                    u16* __restrict__ osc) {
    __shared__ u16 k_lds[224 * 72];   // [perm-row][d], stride 72 (16B-aligned rows)
    __shared__ u16 vT[64 * 232];      // [d][key], natural key order, zero-padded

    int wg = xcd_swz(blockIdx.x, 384);
    int h = wg % NHEADS;
    int bt = wg / NHEADS;
    size_t m_base = (size_t)bt * NPAT;
    int tid = threadIdx.x, l = tid & 63, w = tid >> 6;   // w in 0..7
    int lr = l & 15, lg = l >> 4;

    // prefetch this wave's first Q tile (issue-early: overlaps staging latency)
    bf16x8 q00, q01;
    {
        int qrow = w * 16 + lr; if (qrow > 195) qrow = 195;
        const u16* qs = qkv + (m_base + qrow) * QKV_N + h * 64 + lg * 8;
        q00 = *(const bf16x8*)qs;
        q01 = *(const bf16x8*)(qs + 32);
    }

    // stage K rows 0..223 (zeros for key >= 196) at permuted rows. 8 lanes/row.
    {
        int d0 = (tid & 7) * 8;
#pragma unroll
        for (int it = 0; it < 4; ++it) {
            int n = it * 64 + (tid >> 3);
            if (n < 224) {
                u16x8 val = {};
                if (n < 196)
                    val = *(const u16x8*)(qkv + (m_base + n) * QKV_N + 384 + h * 64 + d0);
                int pr = (2 * (n >> 5) + ((n >> 2) & 1)) * 16 + ((n >> 3) & 3) * 4 + (n & 3);
                *(u16x8*)&k_lds[pr * 72 + d0] = val;
            }
        }
    }
    // stage V transposed: wave w owns d rows w*8..w*8+7; lane = key row.
    {
        int d0 = w * 8;
#pragma unroll
        for (int it = 0; it < 4; ++it) {
            int n = it * 64 + l;
            if (n < 232) {
                u16x8 v0 = {};
                if (n < 196)
                    v0 = *(const u16x8*)(qkv + (m_base + n) * QKV_N + 768 + h * 64 + d0);
#pragma unroll
                for (int j = 0; j < 8; ++j)
                    vT[(d0 + j) * 232 + n] = v0[j];
            }
        }
    }
    __syncthreads();

    // qt = w, then w+8 (waves 5..7 have only one tile)
    attn_qt(k_lds, vT, osc, m_base, h, lr, lg, w, q00, q01);
    int qt1 = w + 8;
    if (qt1 < 13) {
        int qrow = qt1 * 16 + lr; if (qrow > 195) qrow = 195;
        const u16* qs = qkv + (m_base + qrow) * QKV_N + h * 64 + lg * 8;
        attn_qt(k_lds, vT, osc, m_base, h, lr, lg, qt1,
                *(const bf16x8*)qs, *(const bf16x8*)(qs + 32));
    }
}

extern "C" void kernel_launch(void* const* d_in, const int* in_sizes, int n_in,
                              void* d_out, int out_size, void* d_ws, size_t ws_size,
                              hipStream_t stream) {
    const float* x     = (const float*)d_in[0];
    const float* Wqkv  = (const float*)d_in[1];
    const float* bqkv  = (const float*)d_in[2];
    const float* Wproj = (const float*)d_in[3];
    const float* bproj = (const float*)d_in[4];

    // workspace layout (all bf16/u16):
    //   xbf    : M*384      (x in bf16; reused as attention output)
    //   qkvb   : M*1152
    //   wqkvb  : 1152*384
    //   wprojb : 384*384 (col-permuted)
    const size_t need = ((size_t)M_TOTAL * 384 + (size_t)M_TOTAL * QKV_N
                         + (size_t)QKV_N * K_DIM + (size_t)K_DIM * K_DIM) * 2;
    if (ws_size < need) {
        hipMemsetAsync(d_out, 0, (size_t)out_size * 4, stream);
        return;
    }

    u16* xbf    = (u16*)d_ws;
    u16* qkvb   = xbf + (size_t)M_TOTAL * 384;
    u16* wqkvb  = qkvb + (size_t)M_TOTAL * QKV_N;
    u16* wprojb = wqkvb + (size_t)QKV_N * K_DIM;

    cvt_bf16_kern<<<18816, 256, 0, stream>>>(x, xbf, 4816896);
    cvt_bf16_kern<<<216, 256, 0, stream>>>(Wqkv, wqkvb, 55296);
    cvt_wproj_kern<<<576, 256, 0, stream>>>(Wproj, wprojb);

    gemm_kern<QKV_N, true, true><<<7056, 256, 0, stream>>>(xbf, wqkvb, bqkv, qkvb);
    attn_kern<<<3072, 512, 0, stream>>>(qkvb, xbf);
    gemm_kern<384, false, false><<<2352, 256, 0, stream>>>(xbf, wprojb, bproj, (float*)d_out);
}